// Round 4
// baseline (170.172 us; speedup 1.0000x reference)
//
#include <hip/hip_runtime.h>

// Kernel 1: CSR row pointers from sorted segment_ids.
// rowptr[s] = lower_bound(segid, s); rowptr[S] = E. Each edge whose segid
// differs from its predecessor writes the whole gap (covers empty segments).
__global__ __launch_bounds__(256) void build_rowptr_kernel(
    const int* __restrict__ segid, int* __restrict__ rowptr, int E, int S)
{
    const int e = blockIdx.x * blockDim.x + threadIdx.x;
    if (e >= E) return;
    const int cur  = segid[e];
    const int prev = (e == 0) ? -1 : segid[e - 1];
    for (int s = prev + 1; s <= cur; ++s) rowptr[s] = e;
    if (e == E - 1) {
        for (int s = cur + 1; s <= S; ++s) rowptr[s] = E;
    }
}

// Kernel 2: one 16-lane GROUP per segment (4 segments per wave).
// Group g = lanes [16g,16g+16) owns segment 4*wave+g; lane f = lane&15 owns
// float4 slot f of the 64-float row. Each wave VMEM instruction gathers
// 4 edges x 256 B = 1 KB (one edge per group). The rowptr->gidx->gather
// dependence chain is paid once per FOUR segments, there is no cross-lane
// reduction at all (each lane's accumulator is its final (segment,slot) sum),
// and unroll-8 keeps up to 32 edges = 8 KB in flight per wave.
__global__ __launch_bounds__(256) void seg_mean_kernel(
    const float4* __restrict__ values4,   // [N_SRC * 16] float4
    const int*    __restrict__ gidx,
    const int*    __restrict__ rowptr,
    float4*       __restrict__ out4,      // [S * 16] float4
    int S)
{
    const int wave = (blockIdx.x * blockDim.x + threadIdx.x) >> 6;
    const int lane = threadIdx.x & 63;
    const int g    = lane >> 4;           // group = which segment of the 4
    const int f    = lane & 15;           // float4 slot within the row
    const int sg   = (wave << 2) + g;     // this group's segment
    if (sg >= S) return;

    const int start = rowptr[sg];
    const int end   = rowptr[sg + 1];
    const int cnt   = end - start;

    float ax = 0.f, ay = 0.f, az = 0.f, aw = 0.f;

    for (int base = 0; base < cnt; base += 16) {
        const int p     = start + base + f;
        const int myidx = (p < end) ? gidx[p] : 0;   // 16 coalesced idx per group
        const int n     = min(16, cnt - base);
        #pragma unroll 8
        for (int it = 0; it < 16; ++it) {
            if (it < n) {                             // group-uniform predicate
                const int idx = __shfl(myidx, (g << 4) | it);  // in-group broadcast
                const float4 v = values4[(size_t)idx * 16 + f]; // 1 KB / wave instr
                ax += v.x; ay += v.y; az += v.z; aw += v.w;
            }
        }
    }

    const float inv = 1.0f / (float)(cnt > 0 ? cnt : 1);
    float4 o;
    o.x = ax * inv; o.y = ay * inv; o.z = az * inv; o.w = aw * inv;
    out4[(size_t)sg * 16 + f] = o;                    // 4 x 256 B coalesced store
}

extern "C" void kernel_launch(void* const* d_in, const int* in_sizes, int n_in,
                              void* d_out, int out_size, void* d_ws, size_t ws_size,
                              hipStream_t stream) {
    const float4* values4 = (const float4*)d_in[0];  // [N_SRC, 64] f32
    const int*    gidx    = (const int*)d_in[1];     // [E]
    const int*    segid   = (const int*)d_in[2];     // [E] sorted
    float4* out4   = (float4*)d_out;
    int*    rowptr = (int*)d_ws;                     // (S+1) ints of scratch

    const int E = in_sizes[1];
    const int S = out_size / 64;

    build_rowptr_kernel<<<(E + 255) / 256, 256, 0, stream>>>(segid, rowptr, E, S);

    const int segsPerWave  = 4;
    const int wavesNeeded  = (S + segsPerWave - 1) / segsPerWave;
    const int threads      = 256;                    // 4 waves/block
    const int blocks       = (wavesNeeded * 64 + threads - 1) / threads;
    seg_mean_kernel<<<blocks, threads, 0, stream>>>(values4, gidx, rowptr, out4, S);
}

// Round 5
// 164.635 us; speedup vs baseline: 1.0336x; 1.0336x over previous
//
#include <hip/hip_runtime.h>

typedef float f4 __attribute__((ext_vector_type(4)));

// Kernel 1: CSR row pointers from sorted segment_ids.
// rowptr[s] = lower_bound(segid, s); rowptr[S] = E.
__global__ __launch_bounds__(256) void build_rowptr_kernel(
    const int* __restrict__ segid, int* __restrict__ rowptr, int E, int S)
{
    const int e = blockIdx.x * blockDim.x + threadIdx.x;
    if (e >= E) return;
    const int cur  = segid[e];
    const int prev = (e == 0) ? -1 : segid[e - 1];
    for (int s = prev + 1; s <= cur; ++s) rowptr[s] = e;
    if (e == E - 1) {
        for (int s = cur + 1; s <= S; ++s) rowptr[s] = E;
    }
}

// Kernel 2: one 16-lane group per segment (4 segments/wave), lane f = lane&15
// owns float4 slot f of the 64-float row. Streaming arrays (gidx, out) use
// nontemporal access so they don't evict the 256 MB values table from the
// 256 MB Infinity Cache; values loads stay cached (their ~4x reuse is L3's
// job). Gather: one wave VMEM instr = 4 edges x 256 B = 1 KB.
__global__ __launch_bounds__(256) void seg_mean_kernel(
    const f4*  __restrict__ values4,   // [N_SRC * 16] float4
    const int* __restrict__ gidx,
    const int* __restrict__ rowptr,
    f4*        __restrict__ out4,      // [S * 16] float4
    int S)
{
    const int wave = (blockIdx.x * blockDim.x + threadIdx.x) >> 6;
    const int lane = threadIdx.x & 63;
    const int g    = lane >> 4;           // group = which segment of the 4
    const int f    = lane & 15;           // float4 slot within the row
    const int sg   = (wave << 2) + g;     // this group's segment
    if (sg >= S) return;

    const int start = rowptr[sg];
    const int end   = rowptr[sg + 1];
    const int cnt   = end - start;

    f4 acc = {0.f, 0.f, 0.f, 0.f};

    for (int base = 0; base < cnt; base += 16) {
        const int p     = start + base + f;
        const int myidx = (p < end) ? __builtin_nontemporal_load(&gidx[p]) : 0;
        const int n     = min(16, cnt - base);
        #pragma unroll 8
        for (int it = 0; it < 16; ++it) {
            if (it < n) {                              // group-uniform predicate
                const int idx = __shfl(myidx, (g << 4) | it);
                const f4 v = values4[(size_t)idx * 16 + f];  // cached (L3 reuse)
                acc += v;
            }
        }
    }

    const float inv = 1.0f / (float)(cnt > 0 ? cnt : 1);
    f4 o = acc * inv;
    __builtin_nontemporal_store(o, &out4[(size_t)sg * 16 + f]);  // no L3 alloc
}

extern "C" void kernel_launch(void* const* d_in, const int* in_sizes, int n_in,
                              void* d_out, int out_size, void* d_ws, size_t ws_size,
                              hipStream_t stream) {
    const f4*  values4 = (const f4*)d_in[0];   // [N_SRC, 64] f32
    const int* gidx    = (const int*)d_in[1];  // [E]
    const int* segid   = (const int*)d_in[2];  // [E] sorted
    f4*  out4   = (f4*)d_out;
    int* rowptr = (int*)d_ws;                  // (S+1) ints of scratch

    const int E = in_sizes[1];
    const int S = out_size / 64;

    build_rowptr_kernel<<<(E + 255) / 256, 256, 0, stream>>>(segid, rowptr, E, S);

    const int segsPerWave = 4;
    const int wavesNeeded = (S + segsPerWave - 1) / segsPerWave;
    const int threads     = 256;               // 4 waves/block
    const int blocks      = (wavesNeeded * 64 + threads - 1) / threads;
    seg_mean_kernel<<<blocks, threads, 0, stream>>>(values4, gidx, rowptr, out4, S);
}